// Round 9
// baseline (257.555 us; speedup 1.0000x reference)
//
#include <hip/hip_runtime.h>
#include <hip/hip_bf16.h>
#include <type_traits>

#define SQ    2048
#define DIM   1024
#define NH    16
#define HDIM  64
#define BATCH 4

typedef unsigned short u16;
typedef __bf16 bf16x8 __attribute__((ext_vector_type(8)));
typedef float  f32x4  __attribute__((ext_vector_type(4)));
typedef u16    u16x8  __attribute__((ext_vector_type(8)));

#define QSCALE 0.180336880f   // (1/sqrt(64)) * log2(e), folded into Q at GEMM epilogue

__device__ __forceinline__ u16 f2bf(float f) {
  union { float f; unsigned u; } v; v.f = f;
  unsigned r = v.u + 0x7fffu + ((v.u >> 16) & 1u);
  return (u16)(r >> 16);
}

__device__ __forceinline__ float fast_exp2(float x) {
#if __has_builtin(__builtin_amdgcn_exp2f)
  return __builtin_amdgcn_exp2f(x);
#else
  float y;
  asm("v_exp_f32 %0, %1" : "=v"(y) : "v"(x));
  return y;
#endif
}

// async global->LDS, 16B per lane. LDS dest is wave-uniform base + lane*16.
__device__ __forceinline__ void gll16(const u16* g, u16* l) {
  __builtin_amdgcn_global_load_lds((const __attribute__((address_space(1))) void*)g,
                                   (__attribute__((address_space(3))) void*)l,
                                   16, 0, 0);
}

// ---------------------------------------------------------------------------
// x (fp32) -> bf16, vectorized float4 -> ushort4
// ---------------------------------------------------------------------------
__global__ __launch_bounds__(256)
void f32_to_bf16_vec(const float* __restrict__ in, u16* __restrict__ out, int n4)
{
  const int i = blockIdx.x * blockDim.x + threadIdx.x;
  if (i < n4) {
    const float4 v = ((const float4*)in)[i];
    ushort4 o;
    o.x = f2bf(v.x); o.y = f2bf(v.y); o.z = f2bf(v.z); o.w = f2bf(v.w);
    ((ushort4*)out)[i] = o;
  }
}

// ---------------------------------------------------------------------------
// Transpose fp32 [R][C] -> bf16 [C][R] via 32x32 LDS tile (+1 pad)
// ---------------------------------------------------------------------------
__global__ void transpose_f32_bf16(const float* __restrict__ in, u16* __restrict__ out,
                                   int R, int C)
{
  __shared__ u16 tile[32][33];
  const int bx = blockIdx.x * 32, by = blockIdx.y * 32;
  const int tx = threadIdx.x, ty = threadIdx.y;   // (32,8)
  #pragma unroll
  for (int i = 0; i < 32; i += 8)
    tile[ty + i][tx] = f2bf(in[(size_t)(by + ty + i) * C + bx + tx]);
  __syncthreads();
  #pragma unroll
  for (int i = 0; i < 32; i += 8)
    out[(size_t)(bx + ty + i) * R + by + tx] = tile[tx][ty + i];
}

// ---------------------------------------------------------------------------
// OLD GEMM (m97-structure): kept as fallback (unused this round).
// ---------------------------------------------------------------------------
template<int MODE>
__global__ __launch_bounds__(256)
void gemm_bt(const u16* __restrict__ A, const u16* __restrict__ Bt,
             const float* __restrict__ bias, int K,
             u16* __restrict__ o0, u16* __restrict__ o1, float* __restrict__ of)
{
  __shared__ __align__(16) u16 A0[128 * 32], A1[128 * 32];
  __shared__ __align__(16) u16 B0[128 * 32], B1[128 * 32];

  const int t    = threadIdx.x;
  const int lane = t & 63, wave = t >> 6;
  const int l15  = lane & 15, quad = lane >> 4;
  const int wm   = (wave & 1) * 64, wn = (wave >> 1) * 64;
  const int m0   = blockIdx.y * 128, n0 = blockIdx.x * 128;

  const int srow = wave * 32 + (lane >> 2);
  const int scol = (lane & 3) * 8;

  f32x4 acc[4][4] = {};

  for (int k0 = 0; k0 < K; k0 += 64) {
    const u16* ga = A  + (size_t)(m0 + srow) * K + k0 + scol;
    const u16* gb = Bt + (size_t)(n0 + srow) * K + k0 + scol;
    gll16(ga,              &A0[(wave * 32)      * 32]);
    gll16(ga + 32,         &A1[(wave * 32)      * 32]);
    gll16(ga + 16 * K,     &A0[(wave * 32 + 16) * 32]);
    gll16(ga + 16 * K + 32,&A1[(wave * 32 + 16) * 32]);
    gll16(gb,              &B0[(wave * 32)      * 32]);
    gll16(gb + 32,         &B1[(wave * 32)      * 32]);
    gll16(gb + 16 * K,     &B0[(wave * 32 + 16) * 32]);
    gll16(gb + 16 * K + 32,&B1[(wave * 32 + 16) * 32]);
    __syncthreads();

    #pragma unroll
    for (int ks = 0; ks < 2; ++ks) {
      const u16* Als = ks ? A1 : A0;
      const u16* Bls = ks ? B1 : B0;
      bf16x8 af[4], bfr[4];
      #pragma unroll
      for (int i = 0; i < 4; ++i) af[i]  = *(const bf16x8*)&Als[(wm + 16*i + l15) * 32 + quad * 8];
      #pragma unroll
      for (int j = 0; j < 4; ++j) bfr[j] = *(const bf16x8*)&Bls[(wn + 16*j + l15) * 32 + quad * 8];
      #pragma unroll
      for (int i = 0; i < 4; ++i)
        #pragma unroll
        for (int j = 0; j < 4; ++j)
          acc[i][j] = (MODE == 2)
            ? __builtin_amdgcn_mfma_f32_16x16x32_bf16(bfr[j], af[i], acc[i][j], 0, 0, 0)
            : __builtin_amdgcn_mfma_f32_16x16x32_bf16(af[i], bfr[j], acc[i][j], 0, 0, 0);
    }
    __syncthreads();
  }

  if (MODE == 2) {
    #pragma unroll
    for (int j = 0; j < 4; ++j) {
      #pragma unroll
      for (int r = 0; r < 4; ++r) {
        const int d = n0 + wn + 16*j + quad * 4 + r;   // 0..1023 within V
        const float bn = bias[d];
        const int h = d >> 6, hd = d & 63;
        #pragma unroll
        for (int i = 0; i < 4; ++i) {
          const int m = m0 + wm + 16*i + l15;
          const int b = m >> 11, s = m & 2047;
          o0[(((size_t)(b * NH + h)) * HDIM + hd) * SQ + s] = f2bf(acc[i][j][r] + bn);
        }
      }
    }
  } else {
    #pragma unroll
    for (int j = 0; j < 4; ++j) {
      const int n = n0 + wn + 16*j + l15;
      const float bn = bias[n];
      #pragma unroll
      for (int i = 0; i < 4; ++i) {
        #pragma unroll
        for (int r = 0; r < 4; ++r) {
          const int m = m0 + wm + 16*i + quad * 4 + r;
          const float val = acc[i][j][r] + bn;
          if (MODE == 1) {
            const int sec = n >> 10, d = n & 1023;
            const int h = d >> 6, hd = d & 63;
            const int b = m >> 11, s = m & 2047;
            const int bh = b * NH + h;
            if (sec == 0) o0[((size_t)bh * SQ + s) * HDIM + hd] = f2bf(val * QSCALE);
            else          o1[((size_t)bh * SQ + s) * HDIM + hd] = f2bf(val);
          } else {
            of[(size_t)m * DIM + n] = val;
          }
        }
      }
    }
  }
}

// ---------------------------------------------------------------------------
// 256x256 8-wave GEMM, v2 schedule (T2+T3+T4+T5) + T1 XCD swizzle.
// Frozen at r6 config (QK only). See r4/r5 comments for schedule ledger.
// ---------------------------------------------------------------------------
template<int MODE>
__global__ __launch_bounds__(512)
void gemm256(const u16* __restrict__ A, const u16* __restrict__ Bt,
             const float* __restrict__ bias, int K,
             u16* __restrict__ o0, u16* __restrict__ o1, float* __restrict__ of)
{
  __shared__ __align__(16) u16 Als[2][256 * 64];
  __shared__ __align__(16) u16 Bls[2][256 * 64];

  const int t    = threadIdx.x;
  const int lane = t & 63, wave = t >> 6;        // 0..7
  const int l15  = lane & 15, quad = lane >> 4;
  const int wm   = (wave >> 2) * 128;            // 0 / 128
  const int wn   = (wave & 3) * 64;              // 0..192

  const int nwg  = gridDim.x * gridDim.y;
  const int orig = blockIdx.y * gridDim.x + blockIdx.x;
  const int swz  = (orig & 7) * (nwg >> 3) + (orig >> 3);
  const int bx   = swz % gridDim.x, by = swz / gridDim.x;
  const int m0   = by * 256, n0 = bx * 256;

  const int rx  = l15 & 7;
  const int cS0 = ((quad       ^ rx) << 3);
  const int cS1 = (((quad | 4) ^ rx) << 3);

  const int r3 = lane >> 3, c8 = lane & 7;
  const int scol = ((c8 ^ r3) << 3);

  const u16* gA = A  + (size_t)(m0 + wave * 8 + r3) * K + scol;
  const u16* gB = Bt + (size_t)(n0 + wave * 8 + r3) * K + scol;
  const size_t pstride = (size_t)64 * K;

  f32x4 acc[8][4] = {};

  auto stA = [&](int k0, int buf, int p) {
    gll16(gA + (size_t)p * pstride + k0, &Als[buf][(p * 64 + wave * 8) * 64]);
  };
  auto stB = [&](int k0, int buf, int p) {
    gll16(gB + (size_t)p * pstride + k0, &Bls[buf][(p * 64 + wave * 8) * 64]);
  };

  stA(0, 0, 0); stA(0, 0, 2); stB(0, 0, 0); stB(0, 0, 1);
  stB(0, 0, 2); stB(0, 0, 3); stA(0, 0, 1); stA(0, 0, 3);
  asm volatile("s_waitcnt vmcnt(2)" ::: "memory");
  __builtin_amdgcn_s_barrier();
  __builtin_amdgcn_sched_barrier(0);

  const int NT = K >> 6;
  for (int tt = 0; tt < NT; ++tt) {
    const int cur = tt & 1, nxt = cur ^ 1;
    const int k1  = (tt + 1) << 6;
    const bool st = (tt + 1 < NT);
    const u16* Ab = &Als[cur][0];
    const u16* Bb = &Bls[cur][0];
    bf16x8 af[4], bf0[4], bf1[4];

    // ---- phase 0 ----
    #pragma unroll
    for (int nj = 0; nj < 4; ++nj)
      bf0[nj] = *(const bf16x8*)&Bb[(wn + 16 * nj + l15) * 64 + cS0];
    #pragma unroll
    for (int mi = 0; mi < 4; ++mi)
      af[mi] = *(const bf16x8*)&Ab[(wm + 16 * mi + l15) * 64 + cS0];
    if (st) { stA(k1, nxt, 0); stA(k1, nxt, 2); stB(k1, nxt, 0); stB(k1, nxt, 1); }
    __builtin_amdgcn_s_barrier();
    __builtin_amdgcn_s_setprio(1);
    #pragma unroll
    for (int mi = 0; mi < 4; ++mi)
      #pragma unroll
      for (int nj = 0; nj < 4; ++nj)
        acc[mi][nj] = (MODE == 2)
          ? __builtin_amdgcn_mfma_f32_16x16x32_bf16(bf0[nj], af[mi], acc[mi][nj], 0, 0, 0)
          : __builtin_amdgcn_mfma_f32_16x16x32_bf16(af[mi], bf0[nj], acc[mi][nj], 0, 0, 0);
    __builtin_amdgcn_s_setprio(0);
    if (st) asm volatile("s_waitcnt vmcnt(4)" ::: "memory");
    else    asm volatile("s_waitcnt vmcnt(0)" ::: "memory");
    __builtin_amdgcn_s_barrier();
    __builtin_amdgcn_sched_barrier(0);

    // ---- phase 1 ----
    #pragma unroll
    for (int mi = 0; mi < 4; ++mi)
      af[mi] = *(const bf16x8*)&Ab[(wm + 64 + 16 * mi + l15) * 64 + cS0];
    if (st) { stB(k1, nxt, 2); stB(k1, nxt, 3); stA(k1, nxt, 1); stA(k1, nxt, 3); }
    __builtin_amdgcn_s_barrier();
    __builtin_amdgcn_s_setprio(1);
    #pragma unroll
    for (int mi = 0; mi < 4; ++mi)
      #pragma unroll
      for (int nj = 0; nj < 4; ++nj)
        acc[4 + mi][nj] = (MODE == 2)
          ? __builtin_amdgcn_mfma_f32_16x16x32_bf16(bf0[nj], af[mi], acc[4 + mi][nj], 0, 0, 0)
          : __builtin_amdgcn_mfma_f32_16x16x32_bf16(af[mi], bf0[nj], acc[4 + mi][nj], 0, 0, 0);
    __builtin_amdgcn_s_setprio(0);
    __builtin_amdgcn_s_barrier();

    // ---- phase 2 ----
    #pragma unroll
    for (int nj = 0; nj < 4; ++nj)
      bf1[nj] = *(const bf16x8*)&Bb[(wn + 16 * nj + l15) * 64 + cS1];
    #pragma unroll
    for (int mi = 0; mi < 4; ++mi)
      af[mi] = *(const bf16x8*)&Ab[(wm + 16 * mi + l15) * 64 + cS1];
    __builtin_amdgcn_s_barrier();
    __builtin_amdgcn_s_setprio(1);
    #pragma unroll
    for (int mi = 0; mi < 4; ++mi)
      #pragma unroll
      for (int nj = 0; nj < 4; ++nj)
        acc[mi][nj] = (MODE == 2)
          ? __builtin_amdgcn_mfma_f32_16x16x32_bf16(bf1[nj], af[mi], acc[mi][nj], 0, 0, 0)
          : __builtin_amdgcn_mfma_f32_16x16x32_bf16(af[mi], bf1[nj], acc[mi][nj], 0, 0, 0);
    __builtin_amdgcn_s_setprio(0);
    __builtin_amdgcn_s_barrier();

    // ---- phase 3 ----
    #pragma unroll
    for (int mi = 0; mi < 4; ++mi)
      af[mi] = *(const bf16x8*)&Ab[(wm + 64 + 16 * mi + l15) * 64 + cS1];
    __builtin_amdgcn_s_barrier();
    __builtin_amdgcn_s_setprio(1);
    #pragma unroll
    for (int mi = 0; mi < 4; ++mi)
      #pragma unroll
      for (int nj = 0; nj < 4; ++nj)
        acc[4 + mi][nj] = (MODE == 2)
          ? __builtin_amdgcn_mfma_f32_16x16x32_bf16(bf1[nj], af[mi], acc[4 + mi][nj], 0, 0, 0)
          : __builtin_amdgcn_mfma_f32_16x16x32_bf16(af[mi], bf1[nj], acc[4 + mi][nj], 0, 0, 0);
    __builtin_amdgcn_s_setprio(0);
    if (st) asm volatile("s_waitcnt vmcnt(2)" ::: "memory");
    __builtin_amdgcn_s_barrier();
    __builtin_amdgcn_sched_barrier(0);
  }

  // ---- epilogue ----
  if (MODE == 2) {
    #pragma unroll
    for (int j = 0; j < 4; ++j) {
      #pragma unroll
      for (int r = 0; r < 4; ++r) {
        const int d = n0 + wn + 16 * j + quad * 4 + r;
        const float bn = bias[d];
        const int h = d >> 6, hd = d & 63;
        #pragma unroll
        for (int i = 0; i < 8; ++i) {
          const int m = m0 + wm + 16 * i + l15;
          const int b = m >> 11, s = m & 2047;
          o0[(((size_t)(b * NH + h)) * HDIM + hd) * SQ + s] = f2bf(acc[i][j][r] + bn);
        }
      }
    }
  } else {
    #pragma unroll
    for (int j = 0; j < 4; ++j) {
      const int n = n0 + wn + 16 * j + l15;
      const float bn = bias[n];
      #pragma unroll
      for (int i = 0; i < 8; ++i) {
        #pragma unroll
        for (int r = 0; r < 4; ++r) {
          const int m = m0 + wm + 16 * i + quad * 4 + r;
          const float val = acc[i][j][r] + bn;
          if (MODE == 1) {
            const int sec = n >> 10, d = n & 1023;
            const int h = d >> 6, hd = d & 63;
            const int b = m >> 11, s = m & 2047;
            const int bh = b * NH + h;
            if (sec == 0) o0[((size_t)bh * SQ + s) * HDIM + hd] = f2bf(val * QSCALE);
            else          o1[((size_t)bh * SQ + s) * HDIM + hd] = f2bf(val);
          } else {
            of[(size_t)m * DIM + n] = val;
          }
        }
      }
    }
  }
}

// ---------------------------------------------------------------------------
// NEW: 256x128 (BM x BN) 8-wave GEMM, same v2 counted-vmcnt schedule.
// For N=1024 outputs (V, proj): grid (8,32) = 256 blocks = 1/CU (the 256^2
// tile gave only 128 blocks = half-idle GPU; r5 measured that at +9us).
// 8 waves as 2M x 4N: per-wave 128 rows x 32 cols (8 m-frags x 2 n-frags).
// Per-wave M span = 2 A-parts -> phase split by m-half identical to v2.
// Staging 6 gll16/tile (A0..A3, B0..B1). Ledger (all waits >=2.5 phases):
//   prologue: A0 A2 B0 B1 A1 A3, vmcnt(2)            [leaves A1,A3]
//   phase0: read A0/A2+B(ks0); issue A0',A2',B0'; MFMA8; vmcnt(3) [drains
//           this tile's A1,A3; leaves the 3 just issued]
//   phase1: read A1/A3; issue B1',A1',A3'; MFMA8
//   phase2: read ks1 miA; MFMA8
//   phase3: read ks1 miB; MFMA8; vmcnt(2) [drains A0',A2',B0',B1'; leaves
//           A1',A3'] -> boundary state == prologue state
// Tail tile: vmcnt(0) at phase0-end. LDS 96 KiB -> 1 block/CU (grid is 1/CU).
// MODE 0: fp32 row-major store (proj). MODE 2: swapped operands -> V^T.
// ---------------------------------------------------------------------------
template<int MODE>
__global__ __launch_bounds__(512)
void gemm128n(const u16* __restrict__ A, const u16* __restrict__ Bt,
              const float* __restrict__ bias, int K,
              u16* __restrict__ o0, float* __restrict__ of)
{
  __shared__ __align__(16) u16 Als[2][256 * 64];   // 64 KiB
  __shared__ __align__(16) u16 Bls[2][128 * 64];   // 32 KiB

  const int t    = threadIdx.x;
  const int lane = t & 63, wave = t >> 6;        // 0..7
  const int l15  = lane & 15, quad = lane >> 4;
  const int wm   = (wave >> 2) * 128;            // 0 / 128
  const int wn   = (wave & 3) * 32;              // 0..96
  const int m0   = blockIdx.y * 256, n0 = blockIdx.x * 128;

  const int rx  = l15 & 7;
  const int cS0 = ((quad       ^ rx) << 3);
  const int cS1 = (((quad | 4) ^ rx) << 3);

  const int r3 = lane >> 3, c8 = lane & 7;
  const int scol = ((c8 ^ r3) << 3);

  const u16* gA = A  + (size_t)(m0 + wave * 8 + r3) * K + scol;
  const u16* gB = Bt + (size_t)(n0 + wave * 8 + r3) * K + scol;
  const size_t pstride = (size_t)64 * K;

  f32x4 acc[8][2] = {};

  auto stA = [&](int k0, int buf, int p) {     // p in 0..3
    gll16(gA + (size_t)p * pstride + k0, &Als[buf][(p * 64 + wave * 8) * 64]);
  };
  auto stB = [&](int k0, int buf, int p) {     // p in 0..1
    gll16(gB + (size_t)p * pstride + k0, &Bls[buf][(p * 64 + wave * 8) * 64]);
  };

  // prologue: order A0 A2 B0 B1 A1 A3 -> vmcnt(2) leaves A1,A3
  stA(0, 0, 0); stA(0, 0, 2); stB(0, 0, 0); stB(0, 0, 1);
  stA(0, 0, 1); stA(0, 0, 3);
  asm volatile("s_waitcnt vmcnt(2)" ::: "memory");
  __builtin_amdgcn_s_barrier();
  __builtin_amdgcn_sched_barrier(0);

  const int NT = K >> 6;
  for (int tt = 0; tt < NT; ++tt) {
    const int cur = tt & 1, nxt = cur ^ 1;
    const int k1  = (tt + 1) << 6;
    const bool st = (tt + 1 < NT);
    const u16* Ab = &Als[cur][0];
    const u16* Bb = &Bls[cur][0];
    bf16x8 af[4], bf0[2], bf1[2];

    // ---- phase 0: ks0 x mi0-3 (rows wm..wm+63); issue A0',A2',B0' ----
    #pragma unroll
    for (int nj = 0; nj < 2; ++nj)
      bf0[nj] = *(const bf16x8*)&Bb[(wn + 16 * nj + l15) * 64 + cS0];
    #pragma unroll
    for (int mi = 0; mi < 4; ++mi)
      af[mi] = *(const bf16x8*)&Ab[(wm + 16 * mi + l15) * 64 + cS0];
    if (st) { stA(k1, nxt, 0); stA(k1, nxt, 2); stB(k1, nxt, 0); }
    __builtin_amdgcn_s_barrier();
    __builtin_amdgcn_s_setprio(1);
    #pragma unroll
    for (int mi = 0; mi < 4; ++mi)
      #pragma unroll
      for (int nj = 0; nj < 2; ++nj)
        acc[mi][nj] = (MODE == 2)
          ? __builtin_amdgcn_mfma_f32_16x16x32_bf16(bf0[nj], af[mi], acc[mi][nj], 0, 0, 0)
          : __builtin_amdgcn_mfma_f32_16x16x32_bf16(af[mi], bf0[nj], acc[mi][nj], 0, 0, 0);
    __builtin_amdgcn_s_setprio(0);
    if (st) asm volatile("s_waitcnt vmcnt(3)" ::: "memory");
    else    asm volatile("s_waitcnt vmcnt(0)" ::: "memory");
    __builtin_amdgcn_s_barrier();
    __builtin_amdgcn_sched_barrier(0);

    // ---- phase 1: ks0 x mi4-7 (rows wm+64..wm+127); issue B1',A1',A3' ----
    #pragma unroll
    for (int mi = 0; mi < 4; ++mi)
      af[mi] = *(const bf16x8*)&Ab[(wm + 64 + 16 * mi + l15) * 64 + cS0];
    if (st) { stB(k1, nxt, 1); stA(k1, nxt, 1); stA(k1, nxt, 3); }
    __builtin_amdgcn_s_barrier();
    __builtin_amdgcn_s_setprio(1);
    #pragma unroll
    for (int mi = 0; mi < 4; ++mi)
      #pragma unroll
      for (int nj = 0; nj < 2; ++nj)
        acc[4 + mi][nj] = (MODE == 2)
          ? __builtin_amdgcn_mfma_f32_16x16x32_bf16(bf0[nj], af[mi], acc[4 + mi][nj], 0, 0, 0)
          : __builtin_amdgcn_mfma_f32_16x16x32_bf16(af[mi], bf0[nj], acc[4 + mi][nj], 0, 0, 0);
    __builtin_amdgcn_s_setprio(0);
    __builtin_amdgcn_s_barrier();

    // ---- phase 2: ks1 x mi0-3 ----
    #pragma unroll
    for (int nj = 0; nj < 2; ++nj)
      bf1[nj] = *(const bf16x8*)&Bb[(wn + 16 * nj + l15) * 64 + cS1];
    #pragma unroll
    for (int mi = 0; mi < 4; ++mi)
      af[mi] = *(const bf16x8*)&Ab[(wm + 16 * mi + l15) * 64 + cS1];
    __builtin_amdgcn_s_barrier();
    __builtin_amdgcn_s_setprio(1);
    #pragma unroll
    for (int mi = 0; mi < 4; ++mi)
      #pragma unroll
      for (int nj = 0; nj < 2; ++nj)
        acc[mi][nj] = (MODE == 2)
          ? __builtin_amdgcn_mfma_f32_16x16x32_bf16(bf1[nj], af[mi], acc[mi][nj], 0, 0, 0)
          : __builtin_amdgcn_mfma_f32_16x16x32_bf16(af[mi], bf1[nj], acc[mi][nj], 0, 0, 0);
    __builtin_amdgcn_s_setprio(0);
    __builtin_amdgcn_s_barrier();

    // ---- phase 3: ks1 x mi4-7 ----
    #pragma unroll
    for (int mi = 0; mi < 4; ++mi)
      af[mi] = *(const bf16x8*)&Ab[(wm + 64 + 16 * mi + l15) * 64 + cS1];
    __builtin_amdgcn_s_barrier();
    __builtin_amdgcn_s_setprio(1);
    #pragma unroll
    for (int mi = 0; mi < 4; ++mi)
      #pragma unroll
      for (int nj = 0; nj < 2; ++nj)
        acc[4 + mi][nj] = (MODE == 2)
          ? __builtin_amdgcn_mfma_f32_16x16x32_bf16(bf1[nj], af[mi], acc[4 + mi][nj], 0, 0, 0)
          : __builtin_amdgcn_mfma_f32_16x16x32_bf16(af[mi], bf1[nj], acc[4 + mi][nj], 0, 0, 0);
    __builtin_amdgcn_s_setprio(0);
    if (st) asm volatile("s_waitcnt vmcnt(2)" ::: "memory");
    __builtin_amdgcn_s_barrier();
    __builtin_amdgcn_sched_barrier(0);
  }

  // ---- epilogue ----
  if (MODE == 2) {
    // swapped operands: value(i,j,r) = C[m=m0+wm+16i+l15][d=n0+wn+16j+quad*4+r]
    #pragma unroll
    for (int j = 0; j < 2; ++j) {
      #pragma unroll
      for (int r = 0; r < 4; ++r) {
        const int d = n0 + wn + 16 * j + quad * 4 + r;   // 0..1023 within V
        const float bn = bias[d];
        const int h = d >> 6, hd = d & 63;
        #pragma unroll
        for (int i = 0; i < 8; ++i) {
          const int m = m0 + wm + 16 * i + l15;
          const int b = m >> 11, s = m & 2047;
          o0[(((size_t)(b * NH + h)) * HDIM + hd) * SQ + s] = f2bf(acc[i][j][r] + bn);
        }
      }
    }
  } else {
    #pragma unroll
    for (int j = 0; j < 2; ++j) {
      const int n = n0 + wn + 16 * j + l15;
      const float bn = bias[n];
      #pragma unroll
      for (int i = 0; i < 8; ++i) {
        #pragma unroll
        for (int r = 0; r < 4; ++r) {
          const int m = m0 + wm + 16 * i + quad * 4 + r;
          of[(size_t)m * DIM + n] = acc[i][j][r] + bn;
        }
      }
    }
  }
}

// ---------------------------------------------------------------------------
// Causal flash attention v4.5 (r8 config, kept: -1.4us vs v4.4).
// Triple-buffered K/V, counted vmcnt(4), prefetch distance 2.
// ---------------------------------------------------------------------------
__global__ __launch_bounds__(256, 2)
void attn_fused(const u16* __restrict__ q_ws, const u16* __restrict__ k_ws,
                const u16* __restrict__ v_t, u16* __restrict__ y_ws)
{
  __shared__ __align__(16) u16 Kls[3][64 * 64];   // [buf][kv=64][hd=64] swizzled
  __shared__ __align__(16) u16 Vls[3][64 * 64];   // [buf][hd=64][kv=64] swizzled
  __shared__ __align__(16) u16 Pls[4][64 * 64];   // [wave][slot*16+q][kv=64] swizzled

  const int bh = blockIdx.x;
  const int p  = blockIdx.y;                  // 0..7
  const int b = bh >> 4, h = bh & 15;
  const int t = threadIdx.x;
  const int lane = t & 63, wave = t >> 6;     // wave 0..3
  const int l15 = lane & 15, quad = lane >> 4;
  const int rx  = l15 & 7;
  const int cK0 = ((quad      ^ rx) << 3);
  const int cK1 = (((quad | 4) ^ rx) << 3);
  const int pswz = rx << 3;

  const u16* Q  = q_ws + (size_t)bh * SQ * HDIM;
  const u16* Kp = k_ws + (size_t)bh * SQ * HDIM;
  const u16* Vp = v_t  + (size_t)bh * HDIM * SQ;

  const int qtH = 15 - p, qtL = p;
  const int qrowH = qtH * 128 + wave * 32;
  const int qrowL = qtL * 128 + wave * 32;

  bf16x8 qf[4][2];
  #pragma unroll
  for (int s = 0; s < 4; ++s) {
    const int qrow = ((s < 2) ? qrowH : qrowL) + 16 * (s & 1);
    #pragma unroll
    for (int ks = 0; ks < 2; ++ks)
      qf[s][ks] = *(const bf16x8*)&Q[(size_t)(qrow + l15) * HDIM + ks * 32 + quad * 8];
  }

  f32x4 o[4][4] = {};
  float l_q[4] = {};

  const int r3   = lane >> 3;
  const int c8   = lane & 7;
  const int scol = ((c8 ^ r3) << 3);

  auto stage = [&](int kv0, int buf) {
    gll16(&Kp[(size_t)(kv0 + wave*16     + r3) * HDIM + scol], &Kls[buf][(wave*16    ) * 64]);
    gll16(&Kp[(size_t)(kv0 + wave*16 + 8 + r3) * HDIM + scol], &Kls[buf][(wave*16 + 8) * 64]);
    gll16(&Vp[(size_t)(wave*16     + r3) * SQ + kv0 + scol],   &Vls[buf][(wave*16    ) * 64]);
    gll16(&Vp[(size_t)(wave*16 + 8 + r3) * SQ + kv0 + scol],   &Vls[buf][(wave*16 + 8) * 64]);
  };

  auto compute = [&](int kv0, int buf, auto doLc, auto mHc, auto mLc) {
    constexpr bool DO_L = decltype(doLc)::value;
    constexpr bool MH   = decltype(mHc)::value;
    constexpr bool ML   = decltype(mLc)::value;
    constexpr int  NS   = DO_L ? 4 : 2;
    f32x4 st[4][4] = {};
    const u16* Kb = Kls[buf];
    __builtin_amdgcn_s_setprio(1);
    #pragma unroll
    for (int ks = 0; ks < 2; ++ks) {
      const int cs = ks ? cK1 : cK0;
      #pragma unroll
      for (int kt = 0; kt < 4; ++kt) {
        bf16x8 kf = *(const bf16x8*)&Kb[(16*kt + l15) * 64 + cs];
        #pragma unroll
        for (int s = 0; s < NS; ++s)
          st[s][kt] = __builtin_amdgcn_mfma_f32_16x16x32_bf16(kf, qf[s][ks], st[s][kt], 0, 0, 0);
      }
    }
    __builtin_amdgcn_s_setprio(0);

    #pragma unroll
    for (int s = 0; s < NS; ++s) {
      const bool msk = (s < 2) ? MH : ML;
      const int qrow = ((s < 2) ? qrowH : qrowL) + 16 * (s & 1);
      const int q = qrow + l15;
      float rsum = 0.f;
      #pragma unroll
      for (int kt = 0; kt < 4; ++kt)
        #pragma unroll
        for (int r = 0; r < 4; ++r) {
          float pv = fast_exp2(st[s][kt][r]);
          if (msk && (kv0 + 16*kt + quad*4 + r) > q) pv = 0.f;
          st[s][kt][r] = pv;
          rsum += pv;
        }
      l_q[s] += rsum;
    }

    #pragma unroll
    for (int s = 0; s < NS; ++s)
      #pragma unroll
      for (int kt = 0; kt < 4; ++kt) {
        union { __hip_bfloat162 h2[2]; ushort4 u4; } pk;
        pk.h2[0] = __float22bfloat162_rn(make_float2(st[s][kt][0], st[s][kt][1]));
        pk.h2[1] = __float22bfloat162_rn(make_float2(st[s][kt][2], st[s][kt][3]));
        *(ushort4*)&Pls[wave][(16*s + l15) * 64 + ((16*kt + quad*4) ^ pswz)] = pk.u4;
      }

    const u16* Vb = Vls[buf];
    __builtin_amdgcn_s_setprio(1);
    #pragma unroll
    for (int ks = 0; ks < 2; ++ks) {
      const int cs = ks ? cK1 : cK0;
      bf16x8 vf[4];
      #pragma unroll
      for (int n = 0; n < 4; ++n)
        vf[n] = *(const bf16x8*)&Vb[(16*n + l15) * 64 + cs];
      #pragma unroll
      for (int s = 0; s < NS; ++s) {
        bf16x8 pa = *(const bf16x8*)&Pls[wave][(16*s + l15) * 64 + ((ks*32 + quad*8) ^ pswz)];
        #pragma unroll
        for (int n = 0; n < 4; ++n)
          o[s][n] = __builtin_amdgcn_mfma_f32_16x16x32_bf16(pa, vf[n], o[s][n], 0, 0, 0);
      }
    }
    __builtin_amdgcn_s_setprio(0);
  };

  const int ntiles = 2 * qtH + 2;
  const int lastH  = 2 * qtH + (wave >> 1);
  const int lastL  = 2 * qtL + (wave >> 1);

  using Fc = std::integral_constant<bool, false>;
  using Tc = std::integral_constant<bool, true>;

  stage(0, 0);
  stage(64, 1);

  int cur = 0;
  for (int kvt = 0; kvt < ntiles; ++kvt) {
    const int kv0 = kvt * 64;
    if (kvt + 1 < ntiles) asm volatile("s_waitcnt vmcnt(4)" ::: "memory");
    else                  asm volatile("s_waitcnt vmcnt(0)" ::: "memory");
    __builtin_amdgcn_s_barrier();
    __builtin_amdgcn_sched_barrier(0);
    if (kvt + 2 < ntiles) {
      int nb = cur + 2; if (nb >= 3) nb -= 3;
      stage((kvt + 2) * 64, nb);
    }
    if      (kvt <  lastL) compute(kv0, cur, Tc{}, Fc{}, Fc{});
    else if (kvt == lastL) compute(kv0, cur, Tc{}, Fc{}, Tc{});
    else if (kvt <  lastH) compute(kv0, cur, Fc{}, Fc{}, Fc{});
    else if (kvt == lastH) compute(kv0, cur, Fc{}, Tc{}, Fc{});
    if (++cur == 3) cur = 0;
  }

  #pragma unroll
  for (int s = 0; s < 4; ++s) {
    l_q[s] += __shfl_xor(l_q[s], 16);
    l_q[s] += __shfl_xor(l_q[s], 32);
  }
  #pragma unroll
  for (int s = 0; s < 4; ++s) {
    const int qrow = ((s < 2) ? qrowH : qrowL) + 16 * (s & 1);
    #pragma unroll
    for (int r = 0; r < 4; ++r) {
      const float lr = __shfl(l_q[s], quad * 4 + r);
      const float inv = 1.0f / lr;
      const int qg = qrow + quad * 4 + r;
      #pragma unroll
      for (int n = 0; n < 4; ++n)
        y_ws[((size_t)b * SQ + qg) * DIM + h * HDIM + 16*n + l15] = f2bf(o[s][n][r] * inv);
    }
  }
}

// ---------------------------------------------------------------------------
extern "C" void kernel_launch(void* const* d_in, const int* in_sizes, int n_in,
                              void* d_out, int out_size, void* d_ws, size_t ws_size,
                              hipStream_t stream)
{
  const float* x      = (const float*)d_in[0];   // [4,2048,1024] fp32
  const float* W_attn = (const float*)d_in[1];   // [1024,3072]
  const float* b_attn = (const float*)d_in[2];   // [3072]
  const float* W_proj = (const float*)d_in[3];   // [1024,1024]
  const float* b_proj = (const float*)d_in[4];   // [1024]
  float* out = (float*)d_out;                    // [4,2048,1024] fp32

  char* ws = (char*)d_ws;
  u16* WattnT = (u16*)(ws);                  // [3072][1024] bf16, 6.29 MB
  u16* WprojT = (u16*)(ws + 6291456);        // [1024][1024] bf16, 2.10 MB
  u16* xb     = (u16*)(ws + 8388608);        // [8192][1024] bf16, 16.8 MB
  u16* y_ws   = xb;                          // aliases xb (dead after QKV GEMMs)
  u16* q_ws   = (u16*)(ws + 25165824);       // [64][2048][64] bf16
  u16* k_ws   = (u16*)(ws + 41943040);       // [64][2048][64] bf16
  u16* v_tw   = (u16*)(ws + 58720256);       // [64][64][2048] bf16 (V^T)
  // total: 75.5 MB

  const dim3 tb(32, 8);
  transpose_f32_bf16<<<dim3(3 * DIM / 32, DIM / 32), tb, 0, stream>>>(W_attn, WattnT, DIM, 3 * DIM);
  transpose_f32_bf16<<<dim3(DIM / 32, DIM / 32), tb, 0, stream>>>(W_proj, WprojT, DIM, DIM);
  f32_to_bf16_vec<<<(BATCH * SQ * DIM / 4 + 255) / 256, 256, 0, stream>>>(x, xb, BATCH * SQ * DIM / 4);

  // QK sections (N = 2048) on gemm256 v2 + XCD swizzle; 256 blocks = 1/CU.
  gemm256<1><<<dim3(2 * DIM / 256, BATCH * SQ / 256), 512, 0, stream>>>(
      xb, WattnT, b_attn, DIM, q_ws, k_ws, nullptr);
  // V section (N = 1024): new 256x128 geometry -> 256 blocks = 1/CU.
  gemm128n<2><<<dim3(DIM / 128, BATCH * SQ / 256), 512, 0, stream>>>(
      xb, WattnT + (size_t)2048 * DIM, b_attn + 2048, DIM, v_tw, nullptr);

  attn_fused<<<dim3(BATCH * NH, 8), 256, 0, stream>>>(q_ws, k_ws, v_tw, y_ws);

  // proj (N = 1024): same 256x128 geometry.
  gemm128n<0><<<dim3(DIM / 128, BATCH * SQ / 256), 512, 0, stream>>>(
      y_ws, WprojT, b_proj, DIM, nullptr, out);
}

// Round 10
// 248.247 us; speedup vs baseline: 1.0375x; 1.0375x over previous
//
#include <hip/hip_runtime.h>
#include <hip/hip_bf16.h>
#include <type_traits>

#define SQ    2048
#define DIM   1024
#define NH    16
#define HDIM  64
#define BATCH 4

typedef unsigned short u16;
typedef __bf16 bf16x8 __attribute__((ext_vector_type(8)));
typedef float  f32x4  __attribute__((ext_vector_type(4)));
typedef u16    u16x8  __attribute__((ext_vector_type(8)));

#define QSCALE 0.180336880f   // (1/sqrt(64)) * log2(e), folded into Q at GEMM epilogue

__device__ __forceinline__ u16 f2bf(float f) {
  union { float f; unsigned u; } v; v.f = f;
  unsigned r = v.u + 0x7fffu + ((v.u >> 16) & 1u);
  return (u16)(r >> 16);
}

__device__ __forceinline__ float fast_exp2(float x) {
#if __has_builtin(__builtin_amdgcn_exp2f)
  return __builtin_amdgcn_exp2f(x);
#else
  float y;
  asm("v_exp_f32 %0, %1" : "=v"(y) : "v"(x));
  return y;
#endif
}

// async global->LDS, 16B per lane. LDS dest is wave-uniform base + lane*16.
__device__ __forceinline__ void gll16(const u16* g, u16* l) {
  __builtin_amdgcn_global_load_lds((const __attribute__((address_space(1))) void*)g,
                                   (__attribute__((address_space(3))) void*)l,
                                   16, 0, 0);
}

// ---------------------------------------------------------------------------
// x (fp32) -> bf16, vectorized float4 -> ushort4
// ---------------------------------------------------------------------------
__global__ __launch_bounds__(256)
void f32_to_bf16_vec(const float* __restrict__ in, u16* __restrict__ out, int n4)
{
  const int i = blockIdx.x * blockDim.x + threadIdx.x;
  if (i < n4) {
    const float4 v = ((const float4*)in)[i];
    ushort4 o;
    o.x = f2bf(v.x); o.y = f2bf(v.y); o.z = f2bf(v.z); o.w = f2bf(v.w);
    ((ushort4*)out)[i] = o;
  }
}

// ---------------------------------------------------------------------------
// Transpose fp32 [R][C] -> bf16 [C][R] via 32x32 LDS tile (+1 pad)
// ---------------------------------------------------------------------------
__global__ void transpose_f32_bf16(const float* __restrict__ in, u16* __restrict__ out,
                                   int R, int C)
{
  __shared__ u16 tile[32][33];
  const int bx = blockIdx.x * 32, by = blockIdx.y * 32;
  const int tx = threadIdx.x, ty = threadIdx.y;   // (32,8)
  #pragma unroll
  for (int i = 0; i < 32; i += 8)
    tile[ty + i][tx] = f2bf(in[(size_t)(by + ty + i) * C + bx + tx]);
  __syncthreads();
  #pragma unroll
  for (int i = 0; i < 32; i += 8)
    out[(size_t)(bx + ty + i) * R + by + tx] = tile[tx][ty + i];
}

// ---------------------------------------------------------------------------
// OLD GEMM (m97-structure): MODE 0 (proj) and MODE 2 (V) -- r4/r6/r8-proven.
// (r9's 256x128 geometry regressed ~3us each: 0.75 ds_reads/MFMA vs 0.5.)
// ---------------------------------------------------------------------------
template<int MODE>
__global__ __launch_bounds__(256)
void gemm_bt(const u16* __restrict__ A, const u16* __restrict__ Bt,
             const float* __restrict__ bias, int K,
             u16* __restrict__ o0, u16* __restrict__ o1, float* __restrict__ of)
{
  __shared__ __align__(16) u16 A0[128 * 32], A1[128 * 32];
  __shared__ __align__(16) u16 B0[128 * 32], B1[128 * 32];

  const int t    = threadIdx.x;
  const int lane = t & 63, wave = t >> 6;
  const int l15  = lane & 15, quad = lane >> 4;
  const int wm   = (wave & 1) * 64, wn = (wave >> 1) * 64;
  const int m0   = blockIdx.y * 128, n0 = blockIdx.x * 128;

  const int srow = wave * 32 + (lane >> 2);
  const int scol = (lane & 3) * 8;

  f32x4 acc[4][4] = {};

  for (int k0 = 0; k0 < K; k0 += 64) {
    const u16* ga = A  + (size_t)(m0 + srow) * K + k0 + scol;
    const u16* gb = Bt + (size_t)(n0 + srow) * K + k0 + scol;
    gll16(ga,              &A0[(wave * 32)      * 32]);
    gll16(ga + 32,         &A1[(wave * 32)      * 32]);
    gll16(ga + 16 * K,     &A0[(wave * 32 + 16) * 32]);
    gll16(ga + 16 * K + 32,&A1[(wave * 32 + 16) * 32]);
    gll16(gb,              &B0[(wave * 32)      * 32]);
    gll16(gb + 32,         &B1[(wave * 32)      * 32]);
    gll16(gb + 16 * K,     &B0[(wave * 32 + 16) * 32]);
    gll16(gb + 16 * K + 32,&B1[(wave * 32 + 16) * 32]);
    __syncthreads();

    #pragma unroll
    for (int ks = 0; ks < 2; ++ks) {
      const u16* Als = ks ? A1 : A0;
      const u16* Bls = ks ? B1 : B0;
      bf16x8 af[4], bfr[4];
      #pragma unroll
      for (int i = 0; i < 4; ++i) af[i]  = *(const bf16x8*)&Als[(wm + 16*i + l15) * 32 + quad * 8];
      #pragma unroll
      for (int j = 0; j < 4; ++j) bfr[j] = *(const bf16x8*)&Bls[(wn + 16*j + l15) * 32 + quad * 8];
      #pragma unroll
      for (int i = 0; i < 4; ++i)
        #pragma unroll
        for (int j = 0; j < 4; ++j)
          acc[i][j] = (MODE == 2)
            ? __builtin_amdgcn_mfma_f32_16x16x32_bf16(bfr[j], af[i], acc[i][j], 0, 0, 0)
            : __builtin_amdgcn_mfma_f32_16x16x32_bf16(af[i], bfr[j], acc[i][j], 0, 0, 0);
    }
    __syncthreads();
  }

  if (MODE == 2) {
    #pragma unroll
    for (int j = 0; j < 4; ++j) {
      #pragma unroll
      for (int r = 0; r < 4; ++r) {
        const int d = n0 + wn + 16*j + quad * 4 + r;   // 0..1023 within V
        const float bn = bias[d];
        const int h = d >> 6, hd = d & 63;
        #pragma unroll
        for (int i = 0; i < 4; ++i) {
          const int m = m0 + wm + 16*i + l15;
          const int b = m >> 11, s = m & 2047;
          o0[(((size_t)(b * NH + h)) * HDIM + hd) * SQ + s] = f2bf(acc[i][j][r] + bn);
        }
      }
    }
  } else {
    #pragma unroll
    for (int j = 0; j < 4; ++j) {
      const int n = n0 + wn + 16*j + l15;
      const float bn = bias[n];
      #pragma unroll
      for (int i = 0; i < 4; ++i) {
        #pragma unroll
        for (int r = 0; r < 4; ++r) {
          const int m = m0 + wm + 16*i + quad * 4 + r;
          const float val = acc[i][j][r] + bn;
          if (MODE == 1) {
            const int sec = n >> 10, d = n & 1023;
            const int h = d >> 6, hd = d & 63;
            const int b = m >> 11, s = m & 2047;
            const int bh = b * NH + h;
            if (sec == 0) o0[((size_t)bh * SQ + s) * HDIM + hd] = f2bf(val * QSCALE);
            else          o1[((size_t)bh * SQ + s) * HDIM + hd] = f2bf(val);
          } else {
            of[(size_t)m * DIM + n] = val;
          }
        }
      }
    }
  }
}

// ---------------------------------------------------------------------------
// 256x256 8-wave GEMM, v2 schedule (T2+T3+T4+T5) + T1 XCD swizzle.
// Frozen at r6 config (QK only). See r4/r5 comments for schedule ledger.
// ---------------------------------------------------------------------------
template<int MODE>
__global__ __launch_bounds__(512)
void gemm256(const u16* __restrict__ A, const u16* __restrict__ Bt,
             const float* __restrict__ bias, int K,
             u16* __restrict__ o0, u16* __restrict__ o1, float* __restrict__ of)
{
  __shared__ __align__(16) u16 Als[2][256 * 64];
  __shared__ __align__(16) u16 Bls[2][256 * 64];

  const int t    = threadIdx.x;
  const int lane = t & 63, wave = t >> 6;        // 0..7
  const int l15  = lane & 15, quad = lane >> 4;
  const int wm   = (wave >> 2) * 128;            // 0 / 128
  const int wn   = (wave & 3) * 64;              // 0..192

  const int nwg  = gridDim.x * gridDim.y;
  const int orig = blockIdx.y * gridDim.x + blockIdx.x;
  const int swz  = (orig & 7) * (nwg >> 3) + (orig >> 3);
  const int bx   = swz % gridDim.x, by = swz / gridDim.x;
  const int m0   = by * 256, n0 = bx * 256;

  const int rx  = l15 & 7;
  const int cS0 = ((quad       ^ rx) << 3);
  const int cS1 = (((quad | 4) ^ rx) << 3);

  const int r3 = lane >> 3, c8 = lane & 7;
  const int scol = ((c8 ^ r3) << 3);

  const u16* gA = A  + (size_t)(m0 + wave * 8 + r3) * K + scol;
  const u16* gB = Bt + (size_t)(n0 + wave * 8 + r3) * K + scol;
  const size_t pstride = (size_t)64 * K;

  f32x4 acc[8][4] = {};

  auto stA = [&](int k0, int buf, int p) {
    gll16(gA + (size_t)p * pstride + k0, &Als[buf][(p * 64 + wave * 8) * 64]);
  };
  auto stB = [&](int k0, int buf, int p) {
    gll16(gB + (size_t)p * pstride + k0, &Bls[buf][(p * 64 + wave * 8) * 64]);
  };

  stA(0, 0, 0); stA(0, 0, 2); stB(0, 0, 0); stB(0, 0, 1);
  stB(0, 0, 2); stB(0, 0, 3); stA(0, 0, 1); stA(0, 0, 3);
  asm volatile("s_waitcnt vmcnt(2)" ::: "memory");
  __builtin_amdgcn_s_barrier();
  __builtin_amdgcn_sched_barrier(0);

  const int NT = K >> 6;
  for (int tt = 0; tt < NT; ++tt) {
    const int cur = tt & 1, nxt = cur ^ 1;
    const int k1  = (tt + 1) << 6;
    const bool st = (tt + 1 < NT);
    const u16* Ab = &Als[cur][0];
    const u16* Bb = &Bls[cur][0];
    bf16x8 af[4], bf0[4], bf1[4];

    // ---- phase 0 ----
    #pragma unroll
    for (int nj = 0; nj < 4; ++nj)
      bf0[nj] = *(const bf16x8*)&Bb[(wn + 16 * nj + l15) * 64 + cS0];
    #pragma unroll
    for (int mi = 0; mi < 4; ++mi)
      af[mi] = *(const bf16x8*)&Ab[(wm + 16 * mi + l15) * 64 + cS0];
    if (st) { stA(k1, nxt, 0); stA(k1, nxt, 2); stB(k1, nxt, 0); stB(k1, nxt, 1); }
    __builtin_amdgcn_s_barrier();
    __builtin_amdgcn_s_setprio(1);
    #pragma unroll
    for (int mi = 0; mi < 4; ++mi)
      #pragma unroll
      for (int nj = 0; nj < 4; ++nj)
        acc[mi][nj] = (MODE == 2)
          ? __builtin_amdgcn_mfma_f32_16x16x32_bf16(bf0[nj], af[mi], acc[mi][nj], 0, 0, 0)
          : __builtin_amdgcn_mfma_f32_16x16x32_bf16(af[mi], bf0[nj], acc[mi][nj], 0, 0, 0);
    __builtin_amdgcn_s_setprio(0);
    if (st) asm volatile("s_waitcnt vmcnt(4)" ::: "memory");
    else    asm volatile("s_waitcnt vmcnt(0)" ::: "memory");
    __builtin_amdgcn_s_barrier();
    __builtin_amdgcn_sched_barrier(0);

    // ---- phase 1 ----
    #pragma unroll
    for (int mi = 0; mi < 4; ++mi)
      af[mi] = *(const bf16x8*)&Ab[(wm + 64 + 16 * mi + l15) * 64 + cS0];
    if (st) { stB(k1, nxt, 2); stB(k1, nxt, 3); stA(k1, nxt, 1); stA(k1, nxt, 3); }
    __builtin_amdgcn_s_barrier();
    __builtin_amdgcn_s_setprio(1);
    #pragma unroll
    for (int mi = 0; mi < 4; ++mi)
      #pragma unroll
      for (int nj = 0; nj < 4; ++nj)
        acc[4 + mi][nj] = (MODE == 2)
          ? __builtin_amdgcn_mfma_f32_16x16x32_bf16(bf0[nj], af[mi], acc[4 + mi][nj], 0, 0, 0)
          : __builtin_amdgcn_mfma_f32_16x16x32_bf16(af[mi], bf0[nj], acc[4 + mi][nj], 0, 0, 0);
    __builtin_amdgcn_s_setprio(0);
    __builtin_amdgcn_s_barrier();

    // ---- phase 2 ----
    #pragma unroll
    for (int nj = 0; nj < 4; ++nj)
      bf1[nj] = *(const bf16x8*)&Bb[(wn + 16 * nj + l15) * 64 + cS1];
    #pragma unroll
    for (int mi = 0; mi < 4; ++mi)
      af[mi] = *(const bf16x8*)&Ab[(wm + 16 * mi + l15) * 64 + cS1];
    __builtin_amdgcn_s_barrier();
    __builtin_amdgcn_s_setprio(1);
    #pragma unroll
    for (int mi = 0; mi < 4; ++mi)
      #pragma unroll
      for (int nj = 0; nj < 4; ++nj)
        acc[mi][nj] = (MODE == 2)
          ? __builtin_amdgcn_mfma_f32_16x16x32_bf16(bf1[nj], af[mi], acc[mi][nj], 0, 0, 0)
          : __builtin_amdgcn_mfma_f32_16x16x32_bf16(af[mi], bf1[nj], acc[mi][nj], 0, 0, 0);
    __builtin_amdgcn_s_setprio(0);
    __builtin_amdgcn_s_barrier();

    // ---- phase 3 ----
    #pragma unroll
    for (int mi = 0; mi < 4; ++mi)
      af[mi] = *(const bf16x8*)&Ab[(wm + 64 + 16 * mi + l15) * 64 + cS1];
    __builtin_amdgcn_s_barrier();
    __builtin_amdgcn_s_setprio(1);
    #pragma unroll
    for (int mi = 0; mi < 4; ++mi)
      #pragma unroll
      for (int nj = 0; nj < 4; ++nj)
        acc[4 + mi][nj] = (MODE == 2)
          ? __builtin_amdgcn_mfma_f32_16x16x32_bf16(bf1[nj], af[mi], acc[4 + mi][nj], 0, 0, 0)
          : __builtin_amdgcn_mfma_f32_16x16x32_bf16(af[mi], bf1[nj], acc[4 + mi][nj], 0, 0, 0);
    __builtin_amdgcn_s_setprio(0);
    if (st) asm volatile("s_waitcnt vmcnt(2)" ::: "memory");
    __builtin_amdgcn_s_barrier();
    __builtin_amdgcn_sched_barrier(0);
  }

  // ---- epilogue ----
  if (MODE == 2) {
    #pragma unroll
    for (int j = 0; j < 4; ++j) {
      #pragma unroll
      for (int r = 0; r < 4; ++r) {
        const int d = n0 + wn + 16 * j + quad * 4 + r;
        const float bn = bias[d];
        const int h = d >> 6, hd = d & 63;
        #pragma unroll
        for (int i = 0; i < 8; ++i) {
          const int m = m0 + wm + 16 * i + l15;
          const int b = m >> 11, s = m & 2047;
          o0[(((size_t)(b * NH + h)) * HDIM + hd) * SQ + s] = f2bf(acc[i][j][r] + bn);
        }
      }
    }
  } else {
    #pragma unroll
    for (int j = 0; j < 4; ++j) {
      const int n = n0 + wn + 16 * j + l15;
      const float bn = bias[n];
      #pragma unroll
      for (int i = 0; i < 8; ++i) {
        #pragma unroll
        for (int r = 0; r < 4; ++r) {
          const int m = m0 + wm + 16 * i + quad * 4 + r;
          const float val = acc[i][j][r] + bn;
          if (MODE == 1) {
            const int sec = n >> 10, d = n & 1023;
            const int h = d >> 6, hd = d & 63;
            const int b = m >> 11, s = m & 2047;
            const int bh = b * NH + h;
            if (sec == 0) o0[((size_t)bh * SQ + s) * HDIM + hd] = f2bf(val * QSCALE);
            else          o1[((size_t)bh * SQ + s) * HDIM + hd] = f2bf(val);
          } else {
            of[(size_t)m * DIM + n] = val;
          }
        }
      }
    }
  }
}

// ---------------------------------------------------------------------------
// Causal flash attention v4.6: l = P*1 via MFMA (flash row-sum trick).
// v4.5's softmax had `rsum += pv` -- 64 SEQUENTIAL dependent FP adds per
// tile (non-reassociable without fast-math) ~ 256 cyc of pure chain latency,
// comparable to the tile's entire MFMA work. v4.6 computes the row sum on
// the idle MFMA pipe instead: one ones-vector MFMA per ks per slot
// (o_l[s] = mfma(pa, 1, o_l[s]) => C[q][*] = sum_k P[q][k], replicated
// across columns). Bonus: result layout (row = quad*4+r) matches the store
// loop exactly -- the epilogue's 8 shfl_xor + per-element shfl all vanish.
// Triple-buffered K/V with counted vmcnt(4) kept from v4.5 (-1.4us).
// grid = (BATCH*NH, 8); block = 256 (4 waves).
// ---------------------------------------------------------------------------
__global__ __launch_bounds__(256, 2)
void attn_fused(const u16* __restrict__ q_ws, const u16* __restrict__ k_ws,
                const u16* __restrict__ v_t, u16* __restrict__ y_ws)
{
  __shared__ __align__(16) u16 Kls[3][64 * 64];   // [buf][kv=64][hd=64] swizzled
  __shared__ __align__(16) u16 Vls[3][64 * 64];   // [buf][hd=64][kv=64] swizzled
  __shared__ __align__(16) u16 Pls[4][64 * 64];   // [wave][slot*16+q][kv=64] swizzled

  const int bh = blockIdx.x;
  const int p  = blockIdx.y;                  // 0..7
  const int b = bh >> 4, h = bh & 15;
  const int t = threadIdx.x;
  const int lane = t & 63, wave = t >> 6;     // wave 0..3
  const int l15 = lane & 15, quad = lane >> 4;
  const int rx  = l15 & 7;
  const int cK0 = ((quad      ^ rx) << 3);
  const int cK1 = (((quad | 4) ^ rx) << 3);
  const int pswz = rx << 3;

  const u16* Q  = q_ws + (size_t)bh * SQ * HDIM;
  const u16* Kp = k_ws + (size_t)bh * SQ * HDIM;
  const u16* Vp = v_t  + (size_t)bh * HDIM * SQ;

  const int qtH = 15 - p, qtL = p;
  const int qrowH = qtH * 128 + wave * 32;
  const int qrowL = qtL * 128 + wave * 32;

  bf16x8 qf[4][2];
  #pragma unroll
  for (int s = 0; s < 4; ++s) {
    const int qrow = ((s < 2) ? qrowH : qrowL) + 16 * (s & 1);
    #pragma unroll
    for (int ks = 0; ks < 2; ++ks)
      qf[s][ks] = *(const bf16x8*)&Q[(size_t)(qrow + l15) * HDIM + ks * 32 + quad * 8];
  }

  // ones vector for the P*1 row-sum MFMA (bf16 1.0 = 0x3F80)
  bf16x8 onesv;
  {
    union { u16 u; __bf16 b; } one; one.u = 0x3F80;
    #pragma unroll
    for (int i = 0; i < 8; ++i) onesv[i] = one.b;
  }

  f32x4 o[4][4] = {};     // [slot][hd n-tile]
  f32x4 o_l[4] = {};      // [slot] row-sum accumulator (l), replicated cols

  const int r3   = lane >> 3;
  const int c8   = lane & 7;
  const int scol = ((c8 ^ r3) << 3);

  auto stage = [&](int kv0, int buf) {
    gll16(&Kp[(size_t)(kv0 + wave*16     + r3) * HDIM + scol], &Kls[buf][(wave*16    ) * 64]);
    gll16(&Kp[(size_t)(kv0 + wave*16 + 8 + r3) * HDIM + scol], &Kls[buf][(wave*16 + 8) * 64]);
    gll16(&Vp[(size_t)(wave*16     + r3) * SQ + kv0 + scol],   &Vls[buf][(wave*16    ) * 64]);
    gll16(&Vp[(size_t)(wave*16 + 8 + r3) * SQ + kv0 + scol],   &Vls[buf][(wave*16 + 8) * 64]);
  };

  auto compute = [&](int kv0, int buf, auto doLc, auto mHc, auto mLc) {
    constexpr bool DO_L = decltype(doLc)::value;
    constexpr bool MH   = decltype(mHc)::value;
    constexpr bool ML   = decltype(mLc)::value;
    constexpr int  NS   = DO_L ? 4 : 2;
    f32x4 st[4][4] = {};
    const u16* Kb = Kls[buf];
    __builtin_amdgcn_s_setprio(1);
    #pragma unroll
    for (int ks = 0; ks < 2; ++ks) {
      const int cs = ks ? cK1 : cK0;
      #pragma unroll
      for (int kt = 0; kt < 4; ++kt) {
        bf16x8 kf = *(const bf16x8*)&Kb[(16*kt + l15) * 64 + cs];
        #pragma unroll
        for (int s = 0; s < NS; ++s)
          st[s][kt] = __builtin_amdgcn_mfma_f32_16x16x32_bf16(kf, qf[s][ks], st[s][kt], 0, 0, 0);
      }
    }
    __builtin_amdgcn_s_setprio(0);

    // P = exp2(S); masked lanes zeroed. No scalar row-sum chain (see o_l).
    #pragma unroll
    for (int s = 0; s < NS; ++s) {
      const bool msk = (s < 2) ? MH : ML;
      const int qrow = ((s < 2) ? qrowH : qrowL) + 16 * (s & 1);
      const int q = qrow + l15;
      #pragma unroll
      for (int kt = 0; kt < 4; ++kt)
        #pragma unroll
        for (int r = 0; r < 4; ++r) {
          float pv = fast_exp2(st[s][kt][r]);
          if (msk && (kv0 + 16*kt + quad*4 + r) > q) pv = 0.f;
          st[s][kt][r] = pv;
        }
    }

    #pragma unroll
    for (int s = 0; s < NS; ++s)
      #pragma unroll
      for (int kt = 0; kt < 4; ++kt) {
        union { __hip_bfloat162 h2[2]; ushort4 u4; } pk;
        pk.h2[0] = __float22bfloat162_rn(make_float2(st[s][kt][0], st[s][kt][1]));
        pk.h2[1] = __float22bfloat162_rn(make_float2(st[s][kt][2], st[s][kt][3]));
        *(ushort4*)&Pls[wave][(16*s + l15) * 64 + ((16*kt + quad*4) ^ pswz)] = pk.u4;
      }

    const u16* Vb = Vls[buf];
    __builtin_amdgcn_s_setprio(1);
    #pragma unroll
    for (int ks = 0; ks < 2; ++ks) {
      const int cs = ks ? cK1 : cK0;
      bf16x8 vf[4];
      #pragma unroll
      for (int n = 0; n < 4; ++n)
        vf[n] = *(const bf16x8*)&Vb[(16*n + l15) * 64 + cs];
      #pragma unroll
      for (int s = 0; s < NS; ++s) {
        bf16x8 pa = *(const bf16x8*)&Pls[wave][(16*s + l15) * 64 + ((ks*32 + quad*8) ^ pswz)];
        #pragma unroll
        for (int n = 0; n < 4; ++n)
          o[s][n] = __builtin_amdgcn_mfma_f32_16x16x32_bf16(pa, vf[n], o[s][n], 0, 0, 0);
        // l += P * 1  (row sum on the MFMA pipe; all output cols identical)
        o_l[s] = __builtin_amdgcn_mfma_f32_16x16x32_bf16(pa, onesv, o_l[s], 0, 0, 0);
      }
    }
    __builtin_amdgcn_s_setprio(0);
  };

  const int ntiles = 2 * qtH + 2;
  const int lastH  = 2 * qtH + (wave >> 1);
  const int lastL  = 2 * qtL + (wave >> 1);

  using Fc = std::integral_constant<bool, false>;
  using Tc = std::integral_constant<bool, true>;

  stage(0, 0);
  stage(64, 1);

  int cur = 0;
  for (int kvt = 0; kvt < ntiles; ++kvt) {
    const int kv0 = kvt * 64;
    if (kvt + 1 < ntiles) asm volatile("s_waitcnt vmcnt(4)" ::: "memory");
    else                  asm volatile("s_waitcnt vmcnt(0)" ::: "memory");
    __builtin_amdgcn_s_barrier();
    __builtin_amdgcn_sched_barrier(0);
    if (kvt + 2 < ntiles) {
      int nb = cur + 2; if (nb >= 3) nb -= 3;
      stage((kvt + 2) * 64, nb);
    }
    if      (kvt <  lastL) compute(kv0, cur, Tc{}, Fc{}, Fc{});
    else if (kvt == lastL) compute(kv0, cur, Tc{}, Fc{}, Tc{});
    else if (kvt <  lastH) compute(kv0, cur, Fc{}, Fc{}, Fc{});
    else if (kvt == lastH) compute(kv0, cur, Fc{}, Tc{}, Fc{});
    if (++cur == 3) cur = 0;
  }

  // epilogue: l for row (quad*4+r) is o_l[s][r] in this lane's own registers
  // (replicated across l15) -- no cross-lane reduction needed.
  #pragma unroll
  for (int s = 0; s < 4; ++s) {
    const int qrow = ((s < 2) ? qrowH : qrowL) + 16 * (s & 1);
    #pragma unroll
    for (int r = 0; r < 4; ++r) {
      const float inv = 1.0f / o_l[s][r];
      const int qg = qrow + quad * 4 + r;
      #pragma unroll
      for (int n = 0; n < 4; ++n)
        y_ws[((size_t)b * SQ + qg) * DIM + h * HDIM + 16*n + l15] = f2bf(o[s][n][r] * inv);
    }
  }
}

// ---------------------------------------------------------------------------
extern "C" void kernel_launch(void* const* d_in, const int* in_sizes, int n_in,
                              void* d_out, int out_size, void* d_ws, size_t ws_size,
                              hipStream_t stream)
{
  const float* x      = (const float*)d_in[0];   // [4,2048,1024] fp32
  const float* W_attn = (const float*)d_in[1];   // [1024,3072]
  const float* b_attn = (const float*)d_in[2];   // [3072]
  const float* W_proj = (const float*)d_in[3];   // [1024,1024]
  const float* b_proj = (const float*)d_in[4];   // [1024]
  float* out = (float*)d_out;                    // [4,2048,1024] fp32

  char* ws = (char*)d_ws;
  u16* WattnT = (u16*)(ws);                  // [3072][1024] bf16, 6.29 MB
  u16* WprojT = (u16*)(ws + 6291456);        // [1024][1024] bf16, 2.10 MB
  u16* xb     = (u16*)(ws + 8388608);        // [8192][1024] bf16, 16.8 MB
  u16* y_ws   = xb;                          // aliases xb (dead after QKV GEMMs)
  u16* q_ws   = (u16*)(ws + 25165824);       // [64][2048][64] bf16
  u16* k_ws   = (u16*)(ws + 41943040);       // [64][2048][64] bf16
  u16* v_tw   = (u16*)(ws + 58720256);       // [64][64][2048] bf16 (V^T)
  // total: 75.5 MB

  const dim3 tb(32, 8);
  transpose_f32_bf16<<<dim3(3 * DIM / 32, DIM / 32), tb, 0, stream>>>(W_attn, WattnT, DIM, 3 * DIM);
  transpose_f32_bf16<<<dim3(DIM / 32, DIM / 32), tb, 0, stream>>>(W_proj, WprojT, DIM, DIM);
  f32_to_bf16_vec<<<(BATCH * SQ * DIM / 4 + 255) / 256, 256, 0, stream>>>(x, xb, BATCH * SQ * DIM / 4);

  // QK sections (N = 2048) on gemm256 v2 + XCD swizzle; 256 blocks = 1/CU.
  gemm256<1><<<dim3(2 * DIM / 256, BATCH * SQ / 256), 512, 0, stream>>>(
      xb, WattnT, b_attn, DIM, q_ws, k_ws, nullptr);
  // V section (N = 1024) back on gemm_bt (512 blocks = 2/CU, r4/r6/r8-proven).
  gemm_bt<2><<<dim3(DIM / 128, BATCH * SQ / 128), 256, 0, stream>>>(
      xb, WattnT + (size_t)2048 * DIM, b_attn + 2048, DIM, v_tw, nullptr, nullptr);

  attn_fused<<<dim3(BATCH * NH, 8), 256, 0, stream>>>(q_ws, k_ws, v_tw, y_ws);

  // proj (N = 1024) back on gemm_bt.
  gemm_bt<0><<<dim3(DIM / 128, BATCH * SQ / 128), 256, 0, stream>>>(
      y_ws, WprojT, b_proj, DIM, nullptr, nullptr, out);
}